// Round 1
// baseline (592.349 us; speedup 1.0000x reference)
//
#include <hip/hip_runtime.h>

#define BB 32
#define CC 64
#define C2 32
#define HH 56
#define WW 56
#define HW 3136

// ---------------- lepe: depthwise 7x7 conv + bias + bn -> d_out ----------------
__global__ __launch_bounds__(256) void lepe_k(const float* __restrict__ x,
                                              const float* __restrict__ wt,
                                              const float* __restrict__ b,
                                              const float* __restrict__ s,
                                              const float* __restrict__ bb,
                                              float* __restrict__ out) {
    __shared__ float wsm[49];
    const int bc = blockIdx.y;          // b*64 + c
    const int c = bc & 63;
    const int tid = threadIdx.x;
    if (tid < 49) wsm[tid] = wt[c * 49 + tid];
    __syncthreads();
    const int n = blockIdx.x * 256 + tid;
    if (n >= HW) return;
    const int ph = n / WW, pw = n % WW;
    const float* xp = x + (long)bc * HW;
    float acc = 0.f;
    #pragma unroll
    for (int i = 0; i < 7; ++i) {
        const int y = ph + i - 3;
        if (y < 0 || y >= HH) continue;
        #pragma unroll
        for (int j = 0; j < 7; ++j) {
            const int xx = pw + j - 3;
            if (xx < 0 || xx >= WW) continue;
            acc = fmaf(xp[y * WW + xx], wsm[i * 7 + j], acc);
        }
    }
    out[(long)bc * HW + n] = (acc + b[c]) * s[c] + bb[c];
}

// ---------------- q: 32x32 channel matmul + bn, *SCALE ----------------
__global__ __launch_bounds__(256) void q_k(const float* __restrict__ x,
                                           const float* __restrict__ wq,
                                           const float* __restrict__ s,
                                           const float* __restrict__ bb,
                                           float* __restrict__ q) {
    __shared__ float wsm[32 * 32];      // transposed: wsm[i*32+o] = wq[o*32+i]
    const int b = blockIdx.y;
    const int tid = threadIdx.x;
    for (int i = tid; i < 1024; i += 256) wsm[(i & 31) * 32 + (i >> 5)] = wq[i];
    __syncthreads();
    const int n = blockIdx.x * 256 + tid;
    if (n >= HW) return;
    const float* xp = x + (long)b * CC * HW;   // first 32 channels
    float acc[32];
    #pragma unroll
    for (int o = 0; o < 32; ++o) acc[o] = 0.f;
    for (int i = 0; i < 32; ++i) {
        const float xv = xp[i * HW + n];
        #pragma unroll
        for (int o = 0; o < 32; ++o) acc[o] = fmaf(wsm[i * 32 + o], xv, acc[o]);
    }
    float* qp = q + (long)b * C2 * HW + n;
    #pragma unroll
    for (int o = 0; o < 32; ++o)
        qp[o * HW] = (acc[o] * s[o] + bb[o]) * 0.25f;
}

// ---------------- pool: 8x8 mean over second-half channels ----------------
__global__ __launch_bounds__(256) void pool_k(const float* __restrict__ x,
                                              float* __restrict__ pool) {
    const int idx = blockIdx.x * 256 + threadIdx.x;   // b*32*49
    if (idx >= BB * 32 * 49) return;
    const int l = idx % 49;
    const int bi = idx / 49;
    const int i = bi % 32, b = bi / 32;
    const int py = l / 7, px = l % 7;
    const float* xp = x + ((long)b * CC + 32 + i) * HW + py * 8 * WW + px * 8;
    float acc = 0.f;
    #pragma unroll
    for (int y = 0; y < 8; ++y)
        #pragma unroll
        for (int xx = 0; xx < 8; ++xx) acc += xp[y * WW + xx];
    pool[idx] = acc * (1.f / 64.f);
}

// ---------------- wk: 32x32 matmul + bn on pooled 7x7 ----------------
__global__ __launch_bounds__(256) void wk_k(const float* __restrict__ pool,
                                            const float* __restrict__ wk,
                                            const float* __restrict__ s,
                                            const float* __restrict__ bb,
                                            float* __restrict__ kg) {
    const int idx = blockIdx.x * 256 + threadIdx.x;   // b*32*49
    if (idx >= BB * 32 * 49) return;
    const int l = idx % 49;
    const int bo = idx / 49;
    const int o = bo % 32, b = bo / 32;
    const float* pp = pool + (long)b * 32 * 49;
    float acc = 0.f;
    #pragma unroll
    for (int i = 0; i < 32; ++i) acc = fmaf(wk[o * 32 + i], pp[i * 49 + l], acc);
    kg[idx] = acc * s[o] + bb[o];
}

// ---------------- fused attention (qk^T -> wp -> +rpb -> softmax) + dyn_mix ----------------
__global__ __launch_bounds__(256) void attnmix_k(const float* __restrict__ x,
                                                 const float* __restrict__ q,
                                                 const float* __restrict__ kg,
                                                 const float* __restrict__ wp_w,
                                                 const float* __restrict__ wp_b,
                                                 const float* __restrict__ rpb1,
                                                 const float* __restrict__ rpb2,
                                                 float* __restrict__ mix) {
    __shared__ float wp_s[49 * 80];     // transposed + padded: wp_s[l*80+m] = wp_w[m*49+l]
    __shared__ float wpb_s[74];
    __shared__ float kg_s[8 * 52];      // kg_s[c*52+l]
    __shared__ float rpb1_s[81];
    __shared__ float rpb2_s[169];
    const int tid = threadIdx.x;
    const int bg = blockIdx.y;
    const int g = bg & 3, b = bg >> 2;
    for (int i = tid; i < 74 * 49; i += 256) {
        const int m = i / 49, l = i % 49;
        wp_s[l * 80 + m] = wp_w[i];
    }
    if (tid < 74) wpb_s[tid] = wp_b[tid];
    for (int i = tid; i < 8 * 49; i += 256) {
        const int c = i / 49, l = i % 49;
        kg_s[c * 52 + l] = kg[((long)b * 32 + g * 8) * 49 + i];
    }
    if (tid < 81) rpb1_s[tid] = rpb1[g * 81 + tid];
    if (tid < 169) rpb2_s[tid] = rpb2[g * 169 + tid];
    __syncthreads();
    const int n = blockIdx.x * 256 + tid;
    if (n >= HW) return;

    float q8[8];
    #pragma unroll
    for (int c = 0; c < 8; ++c) q8[c] = q[((long)b * C2 + g * 8 + c) * HW + n];

    // wm[m] = wp_b[m] + sum_l wp_w[m,l] * (sum_c q8[c]*kg[c,l])
    float wm[74];
    #pragma unroll
    for (int m = 0; m < 74; ++m) wm[m] = wpb_s[m];
    for (int l = 0; l < 49; ++l) {
        float t = 0.f;
        #pragma unroll
        for (int c = 0; c < 8; ++c) t = fmaf(q8[c], kg_s[c * 52 + l], t);
        #pragma unroll
        for (int m = 0; m < 74; ++m) wm[m] = fmaf(wp_s[l * 80 + m], t, wm[m]);
    }

    // relative position bias (reversed-index formula)
    const int ph = n / WW, pw = n % WW;
    const int yr = HH - 1 - ph, xr = WW - 1 - pw;
    const int rh5 = yr < 2 ? yr : (yr > 53 ? yr - 51 : 2);
    const int rw5 = xr < 2 ? xr : (xr > 53 ? xr - 51 : 2);
    const int rh7 = yr < 3 ? yr : (yr > 52 ? yr - 49 : 3);
    const int rw7 = xr < 3 ? xr : (xr > 52 ? xr - 49 : 3);
    #pragma unroll
    for (int i = 0; i < 5; ++i)
        #pragma unroll
        for (int j = 0; j < 5; ++j)
            wm[i * 5 + j] += rpb1_s[(rh5 + i) * 9 + (rw5 + j)];
    #pragma unroll
    for (int i = 0; i < 7; ++i)
        #pragma unroll
        for (int j = 0; j < 7; ++j)
            wm[25 + i * 7 + j] += rpb2_s[(rh7 + i) * 13 + (rw7 + j)];

    // dual softmax
    float mx1 = -1e30f, mx2 = -1e30f;
    #pragma unroll
    for (int m = 0; m < 25; ++m) mx1 = fmaxf(mx1, wm[m]);
    #pragma unroll
    for (int m = 25; m < 74; ++m) mx2 = fmaxf(mx2, wm[m]);
    float s1 = 0.f, s2 = 0.f;
    #pragma unroll
    for (int m = 0; m < 25; ++m) { wm[m] = __expf(wm[m] - mx1); s1 += wm[m]; }
    #pragma unroll
    for (int m = 25; m < 74; ++m) { wm[m] = __expf(wm[m] - mx2); s2 += wm[m]; }
    const float r1 = 1.f / s1, r2 = 1.f / s2;
    #pragma unroll
    for (int m = 0; m < 25; ++m) wm[m] *= r1;
    #pragma unroll
    for (int m = 25; m < 74; ++m) wm[m] *= r2;

    // dynamic mix: 5x5 over v0 (ch 0..31), 7x7 over v1 (ch 32..63)
    const float* v0 = x + ((long)b * CC + g * 8) * HW;
    const float* v1 = x + ((long)b * CC + 32 + g * 8) * HW;
    float* m0 = mix + ((long)b * CC + g * 8) * HW + n;
    float* m1 = mix + ((long)b * CC + 32 + g * 8) * HW + n;
    #pragma unroll
    for (int ch = 0; ch < 8; ++ch) {
        float a1 = 0.f;
        #pragma unroll
        for (int i = 0; i < 5; ++i) {
            const int y = ph + i - 2;
            if (y < 0 || y >= HH) continue;
            #pragma unroll
            for (int j = 0; j < 5; ++j) {
                const int xx = pw + j - 2;
                if (xx < 0 || xx >= WW) continue;
                a1 = fmaf(wm[i * 5 + j], v0[ch * HW + y * WW + xx], a1);
            }
        }
        m0[ch * HW] = a1;
        float a2 = 0.f;
        #pragma unroll
        for (int i = 0; i < 7; ++i) {
            const int y = ph + i - 3;
            if (y < 0 || y >= HH) continue;
            #pragma unroll
            for (int j = 0; j < 7; ++j) {
                const int xx = pw + j - 3;
                if (xx < 0 || xx >= WW) continue;
                a2 = fmaf(wm[25 + i * 7 + j], v1[ch * HW + y * WW + xx], a2);
            }
        }
        m1[ch * HW] = a2;
    }
}

// ---------------- final: 64x64 channel matmul + bn + lepe add ----------------
__global__ __launch_bounds__(256) void final_k(const float* __restrict__ mix,
                                               const float* __restrict__ dy_w,
                                               const float* __restrict__ s,
                                               const float* __restrict__ bb,
                                               float* __restrict__ out) {
    __shared__ float w_s[64 * 64];      // transposed: w_s[i*64+o] = dy_w[o*64+i]
    const int tid = threadIdx.x;
    const int b = blockIdx.y;
    for (int i = tid; i < 4096; i += 256) w_s[(i & 63) * 64 + (i >> 6)] = dy_w[i];
    __syncthreads();
    const int n = blockIdx.x * 256 + tid;
    if (n >= HW) return;
    const float* mp = mix + (long)b * CC * HW + n;
    float acc[64];
    #pragma unroll
    for (int o = 0; o < 64; ++o) acc[o] = 0.f;
    for (int i = 0; i < 64; ++i) {
        const float v = mp[i * HW];
        #pragma unroll
        for (int o = 0; o < 64; ++o) acc[o] = fmaf(w_s[i * 64 + o], v, acc[o]);
    }
    float* op = out + (long)b * CC * HW + n;
    #pragma unroll
    for (int o = 0; o < 64; ++o)
        op[o * HW] = fmaf(acc[o], s[o], bb[o]) + op[o * HW];
}

extern "C" void kernel_launch(void* const* d_in, const int* in_sizes, int n_in,
                              void* d_out, int out_size, void* d_ws, size_t ws_size,
                              hipStream_t stream) {
    const float* x       = (const float*)d_in[0];
    const float* lepe_w  = (const float*)d_in[1];
    const float* lepe_b  = (const float*)d_in[2];
    const float* lepe_s  = (const float*)d_in[3];
    const float* lepe_bb = (const float*)d_in[4];
    const float* wq_w    = (const float*)d_in[5];
    const float* wq_s    = (const float*)d_in[6];
    const float* wq_bb   = (const float*)d_in[7];
    const float* wk_w    = (const float*)d_in[8];
    const float* wk_s    = (const float*)d_in[9];
    const float* wk_bb   = (const float*)d_in[10];
    const float* wp_w    = (const float*)d_in[11];
    const float* wp_b    = (const float*)d_in[12];
    const float* rpb1    = (const float*)d_in[13];
    const float* rpb2    = (const float*)d_in[14];
    const float* dy_w    = (const float*)d_in[15];
    const float* dy_s    = (const float*)d_in[16];
    const float* dy_bb   = (const float*)d_in[17];
    float* out = (float*)d_out;

    float* ws     = (float*)d_ws;
    float* q_ws   = ws;                               // 32*32*3136
    float* pool_ws = q_ws + 32 * 32 * HW;             // 32*32*49
    float* kg_ws  = pool_ws + 32 * 32 * 49;           // 32*32*49
    float* mix_ws = kg_ws + 32 * 32 * 49;             // 32*64*3136

    const int nTiles = (HW + 255) / 256;              // 13

    lepe_k<<<dim3(nTiles, BB * CC), 256, 0, stream>>>(x, lepe_w, lepe_b, lepe_s, lepe_bb, out);
    q_k<<<dim3(nTiles, BB), 256, 0, stream>>>(x, wq_w, wq_s, wq_bb, q_ws);
    pool_k<<<dim3((BB * 32 * 49 + 255) / 256), 256, 0, stream>>>(x, pool_ws);
    wk_k<<<dim3((BB * 32 * 49 + 255) / 256), 256, 0, stream>>>(pool_ws, wk_w, wk_s, wk_bb, kg_ws);
    attnmix_k<<<dim3(nTiles, BB * 4), 256, 0, stream>>>(x, q_ws, kg_ws, wp_w, wp_b, rpb1, rpb2, mix_ws);
    final_k<<<dim3(nTiles, BB), 256, 0, stream>>>(mix_ws, dy_w, dy_s, dy_bb, out);
}